// Round 5
// baseline (246.883 us; speedup 1.0000x reference)
//
#include <hip/hip_runtime.h>
#include <hip/hip_bf16.h>

// R5: fp32 I/O, bf16 internal. 3 dispatches:
//   gemm<float,0>(x,w_qkv -> qk bf16 [8192][768] (q pre-scaled 0.125), vT [48][64][1024])
//   attn: S^T-trick flash attention — no LDS, no barriers, register-prefetched K/V
//   gemm<ushort,1>(aout,w_proj -> out fp32)
// ws (ushort): qk 6291456 | vT 3145728 | aout 3145728. 25.2 MB.

typedef __attribute__((__ext_vector_type__(8))) __bf16 bf16x8;
typedef __attribute__((__ext_vector_type__(8))) unsigned short ushort8;
typedef __attribute__((__ext_vector_type__(4))) unsigned short ushort4v;
typedef __attribute__((__ext_vector_type__(4))) short short4v;
typedef __attribute__((__ext_vector_type__(4))) float f32x4;

__device__ __forceinline__ f32x4 mfma32(bf16x8 a, bf16x8 b, f32x4 c) {
    return __builtin_amdgcn_mfma_f32_16x16x32_bf16(a, b, c, 0, 0, 0);
}
// K=16 bf16 MFMA: operand k-index = quad*4+j  (matches S^T C-layout registers)
__device__ __forceinline__ f32x4 mfma16(short4v a, short4v b, f32x4 c) {
    return __builtin_amdgcn_mfma_f32_16x16x16bf16_1k(a, b, c, 0, 0, 0);
}

__device__ __forceinline__ unsigned short f2bf(float f) {
    union { float f; unsigned int i; } x; x.f = f;
    unsigned int u = x.i;
    return (unsigned short)((u + 0x7fffu + ((u >> 16) & 1u)) >> 16);
}

__device__ __forceinline__ ushort8 load8_bf16(const float* p) {
    float4 a = *(const float4*)p;
    float4 b = *(const float4*)(p + 4);
    ushort8 r;
    r[0] = f2bf(a.x); r[1] = f2bf(a.y); r[2] = f2bf(a.z); r[3] = f2bf(a.w);
    r[4] = f2bf(b.x); r[5] = f2bf(b.y); r[6] = f2bf(b.z); r[7] = f2bf(b.w);
    return r;
}
__device__ __forceinline__ ushort8 load8_bf16(const unsigned short* p) {
    return *(const ushort8*)p;
}

// C = A[M,K] @ B[N,K]^T + bias. A is TA (fp32 or bf16), B fp32 (inline cvt). 128x128, BK=32.
// MODE 0 (QKV): n<384 -> qk *0.125 ; n<768 -> qk ; n>=768 -> vT transposed. MODE 1: fp32 out.
template <typename TA, int MODE>
__global__ __launch_bounds__(256) void gemm_bt(
    const TA* __restrict__ A,
    const float* __restrict__ B,
    const float* __restrict__ bias,
    unsigned short* __restrict__ qk,
    unsigned short* __restrict__ vT,
    float* __restrict__ out,
    int M, int N, int K)
{
    const int tid  = threadIdx.x;
    const int lane = tid & 63;
    const int wave = tid >> 6;
    const int l15  = lane & 15;
    const int quad = lane >> 4;
    const int m0 = blockIdx.x * 128;
    const int n0 = blockIdx.y * 128;
    const int wm = (wave >> 1) * 64;
    const int wn = (wave & 1) * 64;

    __shared__ __align__(16) unsigned short As[128 * 32];
    __shared__ __align__(16) unsigned short Bs[128 * 32];

    f32x4 acc[4][4];
    #pragma unroll
    for (int i = 0; i < 4; ++i)
        #pragma unroll
        for (int j = 0; j < 4; ++j)
            acc[i][j] = (f32x4){0.f, 0.f, 0.f, 0.f};

    for (int k0 = 0; k0 < K; k0 += 32) {
        #pragma unroll
        for (int t = 0; t < 2; ++t) {
            int i = tid + t * 256;
            ushort8 va = load8_bf16(A + (size_t)(m0 + (i >> 2)) * K + k0 + (i & 3) * 8);
            ushort8 vb = load8_bf16(B + (size_t)(n0 + (i >> 2)) * K + k0 + (i & 3) * 8);
            *(ushort8*)(As + i * 8) = va;
            *(ushort8*)(Bs + i * 8) = vb;
        }
        __syncthreads();

        bf16x8 af[4], bff[4];
        #pragma unroll
        for (int mt = 0; mt < 4; ++mt)
            af[mt] = *(const bf16x8*)(As + (wm + mt * 16 + l15) * 32 + quad * 8);
        #pragma unroll
        for (int nt = 0; nt < 4; ++nt)
            bff[nt] = *(const bf16x8*)(Bs + (wn + nt * 16 + l15) * 32 + quad * 8);
        #pragma unroll
        for (int mt = 0; mt < 4; ++mt)
            #pragma unroll
            for (int nt = 0; nt < 4; ++nt)
                acc[mt][nt] = mfma32(af[mt], bff[nt], acc[mt][nt]);
        __syncthreads();
    }

    if constexpr (MODE == 0) {
        if (n0 < 768) {
            const float scale = (n0 < 384) ? 0.125f : 1.0f;   // q/k regions are 128-aligned
            #pragma unroll
            for (int nt = 0; nt < 4; ++nt) {
                int n = n0 + wn + nt * 16 + l15;
                float bv = bias[n];
                #pragma unroll
                for (int mt = 0; mt < 4; ++mt) {
                    int mbase = m0 + wm + mt * 16 + quad * 4;
                    #pragma unroll
                    for (int r = 0; r < 4; ++r)
                        qk[(size_t)(mbase + r) * 768 + n] = f2bf((acc[mt][nt][r] + bv) * scale);
                }
            }
        } else {
            #pragma unroll
            for (int nt = 0; nt < 4; ++nt) {
                int n = n0 + wn + nt * 16 + l15;
                float bv = bias[n];
                int h = (n - 768) >> 6;
                int d = (n - 768) & 63;
                #pragma unroll
                for (int mt = 0; mt < 4; ++mt) {
                    int mbase = m0 + wm + mt * 16 + quad * 4;
                    int bb = mbase >> 10;
                    int mm = mbase & 1023;
                    ushort4v pk;
                    #pragma unroll
                    for (int r = 0; r < 4; ++r) pk[r] = f2bf(acc[mt][nt][r] + bv);
                    *(ushort4v*)(vT + ((size_t)((bb * 6 + h) * 64 + d) << 10) + mm) = pk;
                }
            }
        }
    } else {
        #pragma unroll
        for (int nt = 0; nt < 4; ++nt) {
            int n = n0 + wn + nt * 16 + l15;
            float bv = bias[n];
            #pragma unroll
            for (int mt = 0; mt < 4; ++mt) {
                int mbase = m0 + wm + mt * 16 + quad * 4;
                #pragma unroll
                for (int r = 0; r < 4; ++r)
                    out[(size_t)(mbase + r) * N + n] = acc[mt][nt][r] + bv;
            }
        }
    }
}

// Flash attention via S^T trick. Block = (q-tile 64, head, batch); 4 waves x 16 q-rows.
// No LDS, no barriers. kv-step 32, double-buffered register prefetch of K + V^T.
// S^T = mfma(K_frag, Q_frag): lane holds P[q=l15][kv=quad*4+r] == B-operand of 16x16x16 MFMA.
// O^T accumulated in C-layout (rows d, cols q) -> packed ushort4 stores.
__global__ __launch_bounds__(256) void attn_fused(
    const unsigned short* __restrict__ qk,
    const unsigned short* __restrict__ vT,
    unsigned short* __restrict__ aout)   // [8192][384] bf16
{
    const int tid  = threadIdx.x;
    const int wave = tid >> 6;
    const int lane = tid & 63;
    const int l15  = lane & 15;
    const int quad = lane >> 4;
    const int qt = blockIdx.x;   // 0..15
    const int h  = blockIdx.y;   // 0..5
    const int b  = blockIdx.z;   // 0..7

    const size_t rowbase = (size_t)b * 1024;
    const unsigned short* Qp  = qk + rowbase * 768 + h * 64;
    const unsigned short* Kp  = Qp + 384;
    const unsigned short* VTh = vT + ((size_t)(b * 6 + h) << 16);   // [64][1024]
    const int q0 = qt * 64 + wave * 16;

    bf16x8 aq0, aq1;
    {
        const unsigned short* qrow = Qp + (size_t)(q0 + l15) * 768 + quad * 8;
        aq0 = *(const bf16x8*)qrow;
        aq1 = *(const bf16x8*)(qrow + 32);
    }

    f32x4 accO[4];
    #pragma unroll
    for (int dt = 0; dt < 4; ++dt) accO[dt] = (f32x4){0.f, 0.f, 0.f, 0.f};
    float lsum = 0.f;

    const unsigned short* Kl = Kp + (size_t)l15 * 768 + quad * 8;      // K row l15 base
    const unsigned short* Vl = VTh + (size_t)l15 * 1024 + quad * 4;    // V^T row l15 base

    // K frags (2 x 16-kv tiles x 2 k-halves) and V^T frags (2 chunks x 4 d-tiles)
    bf16x8 k0a, k0b, k0c, k0d, k1a, k1b, k1c, k1d;
    short4v v0[8], v1[8];

#define LOADK(A0, A1, B0, B1, kv) {                                        \
        const unsigned short* _p = Kl + (size_t)(kv) * 768;                \
        A0 = *(const bf16x8*)_p;  A1 = *(const bf16x8*)(_p + 32);          \
        _p += (size_t)16 * 768;                                            \
        B0 = *(const bf16x8*)_p;  B1 = *(const bf16x8*)(_p + 32); }
#define LOADV(V, kv) {                                                     \
        _Pragma("unroll") for (int t = 0; t < 2; ++t)                      \
        _Pragma("unroll") for (int dt = 0; dt < 4; ++dt)                   \
            V[t * 4 + dt] = *(const short4v*)(Vl + (size_t)dt * 16384 + (kv) + t * 16); }

    auto step = [&](bf16x8 ka, bf16x8 kb, bf16x8 kc, bf16x8 kd, const short4v* vv) {
        f32x4 z0 = (f32x4){0.f, 0.f, 0.f, 0.f};
        f32x4 z1 = (f32x4){0.f, 0.f, 0.f, 0.f};
        z0 = mfma32(ka, aq0, z0); z0 = mfma32(kb, aq1, z0);   // S^T rows kv..kv+15
        z1 = mfma32(kc, aq0, z1); z1 = mfma32(kd, aq1, z1);   // S^T rows kv+16..kv+31
        short4v p0, p1;
        #pragma unroll
        for (int r = 0; r < 4; ++r) {
            float a = z0[r]; a = (a < 0.f) ? 0.f : __expf(a); lsum += a; p0[r] = (short)f2bf(a);
            float c = z1[r]; c = (c < 0.f) ? 0.f : __expf(c); lsum += c; p1[r] = (short)f2bf(c);
        }
        #pragma unroll
        for (int dt = 0; dt < 4; ++dt) accO[dt] = mfma16(vv[dt], p0, accO[dt]);
        #pragma unroll
        for (int dt = 0; dt < 4; ++dt) accO[dt] = mfma16(vv[4 + dt], p1, accO[dt]);
    };

    LOADK(k0a, k0b, k0c, k0d, 0); LOADV(v0, 0);
    for (int kv0 = 0; kv0 < 1024; kv0 += 64) {
        LOADK(k1a, k1b, k1c, k1d, kv0 + 32); LOADV(v1, kv0 + 32);   // prefetch 2nd half
        step(k0a, k0b, k0c, k0d, v0);
        LOADK(k0a, k0b, k0c, k0d, kv0 + 64); LOADV(v0, kv0 + 64);   // prefetch next iter
        step(k1a, k1b, k1c, k1d, v1);                                // (tail reads stay in ws)
    }
#undef LOADK
#undef LOADV

    // Row sums: quads hold disjoint kv partials for column q=l15.
    lsum += __shfl_xor(lsum, 16, 64);
    lsum += __shfl_xor(lsum, 32, 64);
    float inv = 1.0f / lsum;

    unsigned short* orow = aout + (rowbase + q0 + l15) * 384 + h * 64 + quad * 4;
    #pragma unroll
    for (int dt = 0; dt < 4; ++dt) {
        ushort4v pk;
        #pragma unroll
        for (int r = 0; r < 4; ++r) pk[r] = f2bf(accO[dt][r] * inv);
        *(ushort4v*)(orow + dt * 16) = pk;
    }
}

extern "C" void kernel_launch(void* const* d_in, const int* in_sizes, int n_in,
                              void* d_out, int out_size, void* d_ws, size_t ws_size,
                              hipStream_t stream) {
    const float* x      = (const float*)d_in[0];  // [8,1024,384]
    const float* w_qkv  = (const float*)d_in[1];  // [1152,384]
    const float* b_qkv  = (const float*)d_in[2];  // [1152]
    const float* w_proj = (const float*)d_in[3];  // [384,384]
    const float* b_proj = (const float*)d_in[4];  // [384]
    float* out = (float*)d_out;                   // [8,1024,384]

    unsigned short* qk   = (unsigned short*)d_ws;           // 8192*768
    unsigned short* vT   = qk + (size_t)8192 * 768;         // 48*64*1024
    unsigned short* aout = vT + (size_t)48 * 64 * 1024;     // 8192*384

    gemm_bt<float, 0><<<dim3(64, 9), 256, 0, stream>>>(
        x, w_qkv, b_qkv, qk, vT, nullptr, 8192, 1152, 384);
    attn_fused<<<dim3(16, 6, 8), 256, 0, stream>>>(qk, vT, aout);
    gemm_bt<unsigned short, 1><<<dim3(64, 3), 256, 0, stream>>>(
        aout, w_proj, b_proj, nullptr, nullptr, out, 8192, 384, 384);
}

// Round 7
// 138.043 us; speedup vs baseline: 1.7884x; 1.7884x over previous
//
#include <hip/hip_runtime.h>
#include <hip/hip_bf16.h>

// R7 = R6 with the missing `+ h*64` head offset in the attn Q-fragment load fixed.
//   cvt(x,wq,wp -> bf16)
//   gemm<0>: qkv GEMM, epilogue writes q row-major (pre-scaled 0.125), K and V in
//            MFMA-operand-order slabs per (b,h) so attn can DMA them straight to LDS.
//   attn:    m97-style LDS staging (global_load_lds 16B), S^T trick + mfma16 PV
//            (lane mappings validated end-to-end in R5), no P round-trip, no fences.
//   gemm<1>: proj -> fp32 out.
// ws (ushort elems): qg 3145728 | kg 3145728 | vg 3145728 | aout 3145728 | xb 3145728
//                    | wqb 442368 | wpb 147456  => 32.5 MB.

typedef __attribute__((__ext_vector_type__(8))) __bf16 bf16x8;
typedef __attribute__((__ext_vector_type__(8))) unsigned short ushort8;
typedef __attribute__((__ext_vector_type__(4))) unsigned short ushort4v;
typedef __attribute__((__ext_vector_type__(4))) short short4v;
typedef __attribute__((__ext_vector_type__(4))) float f32x4;

#define NX 3145728   // 8192*384
#define NQ 442368    // 1152*384
#define NP 147456    // 384*384

__device__ __forceinline__ f32x4 mfma32(bf16x8 a, bf16x8 b, f32x4 c) {
    return __builtin_amdgcn_mfma_f32_16x16x32_bf16(a, b, c, 0, 0, 0);
}
__device__ __forceinline__ f32x4 mfma16(short4v a, short4v b, f32x4 c) {
    return __builtin_amdgcn_mfma_f32_16x16x16bf16_1k(a, b, c, 0, 0, 0);
}

__device__ __forceinline__ unsigned short f2bf(float f) {
    union { float f; unsigned int i; } x; x.f = f;
    unsigned int u = x.i;
    return (unsigned short)((u + 0x7fffu + ((u >> 16) & 1u)) >> 16);
}

__device__ __forceinline__ void dma16(const unsigned short* g, unsigned short* l) {
    __builtin_amdgcn_global_load_lds(
        (const __attribute__((address_space(1))) unsigned int*)g,
        (__attribute__((address_space(3))) unsigned int*)l, 16, 0, 0);
}

// fp32 -> bf16 for x, w_qkv, w_proj. 4 elems/thread.
__global__ __launch_bounds__(256) void cvt_bf16(
    const float* __restrict__ x, const float* __restrict__ wq, const float* __restrict__ wp,
    unsigned short* __restrict__ xb, unsigned short* __restrict__ wqb, unsigned short* __restrict__ wpb)
{
    int i = blockIdx.x * 256 + threadIdx.x;
    const float* src; unsigned short* dst; int off;
    if (i < NX / 4)              { src = x;  dst = xb;  off = i * 4; }
    else if (i < (NX + NQ) / 4)  { src = wq; dst = wqb; off = i * 4 - NX; }
    else                         { src = wp; dst = wpb; off = i * 4 - NX - NQ; }
    float4 v = *(const float4*)(src + off);
    ushort4v r;
    r[0] = f2bf(v.x); r[1] = f2bf(v.y); r[2] = f2bf(v.z); r[3] = f2bf(v.w);
    *(ushort4v*)(dst + off) = r;
}

// C = A[M,K] @ B[N,K]^T + bias. bf16 in, fp32 acc, 128x128 tile, BK=32, DMA staging (m97).
// MODE 0 (QKV): n<384 -> qg row-major *0.125 ; 384..768 -> kg operand-order ; >=768 -> vg.
//   kg slab (b,h) [64 kt][2 half][4 quad][16 l15][8 j]: K[kv=kt*16+l15][c=half*32+quad*8+j]
//   vg slab (b,h) [16 c][4 jt][4 dt][4 quad][16 l15][4 j]: V^T[d=dt*16+l15][kv=c*64+jt*16+quad*4+j]
// MODE 1 (proj): fp32 out + bias.
template <int MODE>
__global__ __launch_bounds__(256) void gemm_bt(
    const unsigned short* __restrict__ A,
    const unsigned short* __restrict__ B,
    const float* __restrict__ bias,
    unsigned short* __restrict__ qg,
    unsigned short* __restrict__ kg,
    unsigned short* __restrict__ vg,
    float* __restrict__ out,
    int M, int N, int K)
{
    const int tid  = threadIdx.x;
    const int lane = tid & 63;
    const int wave = tid >> 6;
    const int l15  = lane & 15;
    const int quad = lane >> 4;
    const int m0 = blockIdx.x * 128;
    const int n0 = blockIdx.y * 128;
    const int wm = (wave >> 1) * 64;
    const int wn = (wave & 1) * 64;

    __shared__ __align__(16) unsigned short As[128 * 32];
    __shared__ __align__(16) unsigned short Bs[128 * 32];

    f32x4 acc[4][4];
    #pragma unroll
    for (int i = 0; i < 4; ++i)
        #pragma unroll
        for (int j = 0; j < 4; ++j)
            acc[i][j] = (f32x4){0.f, 0.f, 0.f, 0.f};

    for (int k0 = 0; k0 < K; k0 += 32) {
        // 512 x 16B chunks per tile; chunk i -> row i>>2, col (i&3)*8, LDS elems i*8.
        #pragma unroll
        for (int t = 0; t < 2; ++t) {
            int i = tid + t * 256;
            dma16(A + (size_t)(m0 + (i >> 2)) * K + k0 + (i & 3) * 8, As + t * 2048 + wave * 512);
            dma16(B + (size_t)(n0 + (i >> 2)) * K + k0 + (i & 3) * 8, Bs + t * 2048 + wave * 512);
        }
        __syncthreads();   // drains vmcnt; tiles valid

        bf16x8 af[4], bff[4];
        #pragma unroll
        for (int mt = 0; mt < 4; ++mt)
            af[mt] = *(const bf16x8*)(As + (wm + mt * 16 + l15) * 32 + quad * 8);
        #pragma unroll
        for (int nt = 0; nt < 4; ++nt)
            bff[nt] = *(const bf16x8*)(Bs + (wn + nt * 16 + l15) * 32 + quad * 8);
        #pragma unroll
        for (int mt = 0; mt < 4; ++mt)
            #pragma unroll
            for (int nt = 0; nt < 4; ++nt)
                acc[mt][nt] = mfma32(af[mt], bff[nt], acc[mt][nt]);
        __syncthreads();
    }

    if constexpr (MODE == 0) {
        if (n0 < 384) {            // Q region: row-major, pre-scaled
            #pragma unroll
            for (int nt = 0; nt < 4; ++nt) {
                int n = n0 + wn + nt * 16 + l15;
                float bv = bias[n];
                #pragma unroll
                for (int mt = 0; mt < 4; ++mt) {
                    int mbase = m0 + wm + mt * 16 + quad * 4;
                    #pragma unroll
                    for (int r = 0; r < 4; ++r)
                        qg[(size_t)(mbase + r) * 384 + n] = f2bf((acc[mt][nt][r] + bv) * 0.125f);
                }
            }
        } else if (n0 < 768) {     // K region: operand-order slabs
            #pragma unroll
            for (int nt = 0; nt < 4; ++nt) {
                int n = n0 + wn + nt * 16 + l15;
                float bv = bias[n];
                int c2 = n - 384;
                int h = c2 >> 6, ck = c2 & 63;
                int half = ck >> 5, qd = (ck >> 3) & 3, j = ck & 7;
                #pragma unroll
                for (int mt = 0; mt < 4; ++mt) {
                    int mbase = m0 + wm + mt * 16 + quad * 4;
                    #pragma unroll
                    for (int r = 0; r < 4; ++r) {
                        int tok = mbase + r;
                        int b = tok >> 10, kv = tok & 1023;
                        int kt = kv >> 4, lk = kv & 15;
                        kg[(size_t)(b * 6 + h) * 65536 +
                           ((((size_t)kt * 2 + half) * 4 + qd) * 16 + lk) * 8 + j]
                            = f2bf(acc[mt][nt][r] + bv);
                    }
                }
            }
        } else {                   // V region: operand-order slabs, packed r-contiguous
            #pragma unroll
            for (int nt = 0; nt < 4; ++nt) {
                int n = n0 + wn + nt * 16 + l15;
                float bv = bias[n];
                int c2 = n - 768;
                int h = c2 >> 6, d = c2 & 63;
                int dt = d >> 4, lv = d & 15;
                #pragma unroll
                for (int mt = 0; mt < 4; ++mt) {
                    int mbase = m0 + wm + mt * 16 + quad * 4;   // multiple of 4
                    int b = mbase >> 10, kvb = mbase & 1023;
                    int cc = kvb >> 6, jt = (kvb >> 4) & 3, qd = (kvb >> 2) & 3;
                    ushort4v pk;
                    #pragma unroll
                    for (int r = 0; r < 4; ++r) pk[r] = f2bf(acc[mt][nt][r] + bv);
                    *(ushort4v*)(vg + (size_t)(b * 6 + h) * 65536 + (size_t)cc * 4096 +
                                 (((jt * 4 + dt) * 4 + qd) * 16 + lv) * 4) = pk;
                }
            }
        }
    } else {
        #pragma unroll
        for (int nt = 0; nt < 4; ++nt) {
            int n = n0 + wn + nt * 16 + l15;
            float bv = bias[n];
            #pragma unroll
            for (int mt = 0; mt < 4; ++mt) {
                int mbase = m0 + wm + mt * 16 + quad * 4;
                #pragma unroll
                for (int r = 0; r < 4; ++r)
                    out[(size_t)(mbase + r) * N + n] = acc[mt][nt][r] + bv;
            }
        }
    }
}

// Flash attention, LDS-staged (m97 pattern). Block = (qt 64 rows, h, b); 4 waves x 16 q.
// kv-chunk 64: K 8KB + V 8KB DMA'd per chunk; 4 inner steps of 16 kv.
// S^T trick + mfma16 PV; lane mappings identical to R5 (validated).
__global__ __launch_bounds__(256) void attn_fused(
    const unsigned short* __restrict__ qg,
    const unsigned short* __restrict__ kg,
    const unsigned short* __restrict__ vg,
    unsigned short* __restrict__ aout)   // [8192][384] bf16
{
    const int tid  = threadIdx.x;
    const int wave = tid >> 6;
    const int lane = tid & 63;
    const int l15  = lane & 15;
    const int quad = lane >> 4;
    const int qt = blockIdx.x;   // 0..15
    const int h  = blockIdx.y;   // 0..5
    const int b  = blockIdx.z;   // 0..7

    const size_t rowbase = (size_t)b * 1024;
    const unsigned short* Kslab = kg + (size_t)(b * 6 + h) * 65536;
    const unsigned short* Vslab = vg + (size_t)(b * 6 + h) * 65536;
    const int q0 = qt * 64 + wave * 16;

    __shared__ __align__(16) unsigned short Kb[4096];
    __shared__ __align__(16) unsigned short Vb[4096];

    bf16x8 aq0, aq1;
    {
        const unsigned short* qrow = qg + (rowbase + q0 + l15) * 384 + h * 64 + quad * 8;  // FIX: + h*64
        aq0 = *(const bf16x8*)qrow;
        aq1 = *(const bf16x8*)(qrow + 32);
    }

    f32x4 accO[4];
    #pragma unroll
    for (int dt = 0; dt < 4; ++dt) accO[dt] = (f32x4){0.f, 0.f, 0.f, 0.f};
    float lsum = 0.f;

    for (int c = 0; c < 16; ++c) {
        // Stage chunk c: contiguous 4096-elem copies (operand-order preserved by DMA).
        #pragma unroll
        for (int t = 0; t < 2; ++t) {
            int i = tid + t * 256;
            dma16(Kslab + (size_t)c * 4096 + i * 8, Kb + t * 2048 + wave * 512);
            dma16(Vslab + (size_t)c * 4096 + i * 8, Vb + t * 2048 + wave * 512);
        }
        __syncthreads();   // drains vmcnt; Kb/Vb valid

        #pragma unroll
        for (int kt = 0; kt < 4; ++kt) {
            bf16x8 ka = *(const bf16x8*)(Kb + (((kt * 2 + 0) * 4 + quad) * 16 + l15) * 8);
            bf16x8 kb = *(const bf16x8*)(Kb + (((kt * 2 + 1) * 4 + quad) * 16 + l15) * 8);
            f32x4 z = (f32x4){0.f, 0.f, 0.f, 0.f};
            z = mfma32(ka, aq0, z);
            z = mfma32(kb, aq1, z);    // S^T[kv=quad*4+r][q=l15]

            short4v p;
            #pragma unroll
            for (int r = 0; r < 4; ++r) {
                float s = z[r];
                s = (s < 0.f) ? 0.f : __expf(s);   // threshold mask -> exact 0 (matches ref)
                lsum += s;
                p[r] = (short)f2bf(s);
            }
            #pragma unroll
            for (int dt = 0; dt < 4; ++dt) {
                short4v vv = *(const short4v*)(Vb + (((kt * 4 + dt) * 4 + quad) * 16 + l15) * 4);
                accO[dt] = mfma16(vv, p, accO[dt]);
            }
        }
        __syncthreads();   // reads done before next chunk overwrites
    }

    lsum += __shfl_xor(lsum, 16, 64);
    lsum += __shfl_xor(lsum, 32, 64);
    float inv = 1.0f / lsum;

    unsigned short* orow = aout + (rowbase + q0 + l15) * 384 + h * 64 + quad * 4;
    #pragma unroll
    for (int dt = 0; dt < 4; ++dt) {
        ushort4v pk;
        #pragma unroll
        for (int r = 0; r < 4; ++r) pk[r] = f2bf(accO[dt][r] * inv);
        *(ushort4v*)(orow + dt * 16) = pk;
    }
}

extern "C" void kernel_launch(void* const* d_in, const int* in_sizes, int n_in,
                              void* d_out, int out_size, void* d_ws, size_t ws_size,
                              hipStream_t stream) {
    const float* x      = (const float*)d_in[0];  // [8,1024,384]
    const float* w_qkv  = (const float*)d_in[1];  // [1152,384]
    const float* b_qkv  = (const float*)d_in[2];  // [1152]
    const float* w_proj = (const float*)d_in[3];  // [384,384]
    const float* b_proj = (const float*)d_in[4];  // [384]
    float* out = (float*)d_out;                   // [8,1024,384]

    unsigned short* qg   = (unsigned short*)d_ws;            // 8192*384
    unsigned short* kgp  = qg   + (size_t)NX;                // 48*65536
    unsigned short* vgp  = kgp  + (size_t)NX;                // 48*65536
    unsigned short* aout = vgp  + (size_t)NX;                // 8192*384
    unsigned short* xb   = aout + (size_t)NX;                // 8192*384
    unsigned short* wqb  = xb   + (size_t)NX;                // 1152*384
    unsigned short* wpb  = wqb  + (size_t)NQ;                // 384*384

    cvt_bf16<<<3648, 256, 0, stream>>>(x, w_qkv, w_proj, xb, wqb, wpb);
    gemm_bt<0><<<dim3(64, 9), 256, 0, stream>>>(
        xb, wqb, b_qkv, qg, kgp, vgp, nullptr, 8192, 1152, 384);
    attn_fused<<<dim3(16, 6, 8), 256, 0, stream>>>(qg, kgp, vgp, aout);
    gemm_bt<1><<<dim3(64, 3), 256, 0, stream>>>(
        aout, wpb, b_proj, nullptr, nullptr, nullptr, out, 8192, 384, 384);
}

// Round 8
// 132.635 us; speedup vs baseline: 1.8614x; 1.0408x over previous
//
#include <hip/hip_runtime.h>
#include <hip/hip_bf16.h>

// R8 = R7 with gemm<0> (QKV) retiled 128x128 -> 256x128 @ 512 threads (8 waves, 4x2 of 64x64).
// Everything else (cvt, attn, proj gemm 128x128 @ 256 thr) identical to R7 for attribution.
//   cvt(x,wq,wp -> bf16)
//   gemm<0,256>: qkv GEMM; epilogue: q row-major (pre-scaled 0.125), K/V in MFMA-operand-order
//                slabs per (b,h) so attn DMAs them straight to LDS.
//   attn:        m97-style LDS staging, S^T trick + mfma16 PV, no fences (R5-validated mappings).
//   gemm<1,128>: proj -> fp32 out.
// ws (ushort elems): qg 3145728 | kg 3145728 | vg 3145728 | aout 3145728 | xb 3145728
//                    | wqb 442368 | wpb 147456  => 32.5 MB.

typedef __attribute__((__ext_vector_type__(8))) __bf16 bf16x8;
typedef __attribute__((__ext_vector_type__(8))) unsigned short ushort8;
typedef __attribute__((__ext_vector_type__(4))) unsigned short ushort4v;
typedef __attribute__((__ext_vector_type__(4))) short short4v;
typedef __attribute__((__ext_vector_type__(4))) float f32x4;

#define NX 3145728   // 8192*384
#define NQ 442368    // 1152*384
#define NP 147456    // 384*384

__device__ __forceinline__ f32x4 mfma32(bf16x8 a, bf16x8 b, f32x4 c) {
    return __builtin_amdgcn_mfma_f32_16x16x32_bf16(a, b, c, 0, 0, 0);
}
__device__ __forceinline__ f32x4 mfma16(short4v a, short4v b, f32x4 c) {
    return __builtin_amdgcn_mfma_f32_16x16x16bf16_1k(a, b, c, 0, 0, 0);
}

__device__ __forceinline__ unsigned short f2bf(float f) {
    union { float f; unsigned int i; } x; x.f = f;
    unsigned int u = x.i;
    return (unsigned short)((u + 0x7fffu + ((u >> 16) & 1u)) >> 16);
}

__device__ __forceinline__ void dma16(const unsigned short* g, unsigned short* l) {
    __builtin_amdgcn_global_load_lds(
        (const __attribute__((address_space(1))) unsigned int*)g,
        (__attribute__((address_space(3))) unsigned int*)l, 16, 0, 0);
}

// fp32 -> bf16 for x, w_qkv, w_proj. 4 elems/thread.
__global__ __launch_bounds__(256) void cvt_bf16(
    const float* __restrict__ x, const float* __restrict__ wq, const float* __restrict__ wp,
    unsigned short* __restrict__ xb, unsigned short* __restrict__ wqb, unsigned short* __restrict__ wpb)
{
    int i = blockIdx.x * 256 + threadIdx.x;
    const float* src; unsigned short* dst; int off;
    if (i < NX / 4)              { src = x;  dst = xb;  off = i * 4; }
    else if (i < (NX + NQ) / 4)  { src = wq; dst = wqb; off = i * 4 - NX; }
    else                         { src = wp; dst = wpb; off = i * 4 - NX - NQ; }
    float4 v = *(const float4*)(src + off);
    ushort4v r;
    r[0] = f2bf(v.x); r[1] = f2bf(v.y); r[2] = f2bf(v.z); r[3] = f2bf(v.w);
    *(ushort4v*)(dst + off) = r;
}

// C = A[M,K] @ B[N,K]^T + bias. bf16 in, fp32 acc, TMx128 tile, BK=32, DMA staging (m97).
// THREADS = 2*TM (512 for TM=256 -> 8 waves 4x2; 256 for TM=128 -> 4 waves 2x2).
// MODE 0 (QKV): n<384 -> qg row-major *0.125 ; 384..768 -> kg operand-order ; >=768 -> vg.
//   kg slab (b,h) [64 kt][2 half][4 quad][16 l15][8 j]: K[kv=kt*16+l15][c=half*32+quad*8+j]
//   vg slab (b,h) [16 c][4 jt][4 dt][4 quad][16 l15][4 j]: V^T[d=dt*16+l15][kv=c*64+jt*16+quad*4+j]
// MODE 1 (proj): fp32 out + bias.
template <int MODE, int TM>
__global__ __launch_bounds__(TM * 2) void gemm_bt(
    const unsigned short* __restrict__ A,
    const unsigned short* __restrict__ B,
    const float* __restrict__ bias,
    unsigned short* __restrict__ qg,
    unsigned short* __restrict__ kg,
    unsigned short* __restrict__ vg,
    float* __restrict__ out,
    int M, int N, int K)
{
    const int tid  = threadIdx.x;
    const int lane = tid & 63;
    const int wave = tid >> 6;
    const int l15  = lane & 15;
    const int quad = lane >> 4;
    const int m0 = blockIdx.x * TM;
    const int n0 = blockIdx.y * 128;
    const int wm = (wave >> 1) * 64;     // covers TM via TM/64 wave-rows
    const int wn = (wave & 1) * 64;

    __shared__ __align__(16) unsigned short As[TM * 32];
    __shared__ __align__(16) unsigned short Bs[128 * 32];

    f32x4 acc[4][4];
    #pragma unroll
    for (int i = 0; i < 4; ++i)
        #pragma unroll
        for (int j = 0; j < 4; ++j)
            acc[i][j] = (f32x4){0.f, 0.f, 0.f, 0.f};

    for (int k0 = 0; k0 < K; k0 += 32) {
        // A: TM*4 16B chunks, 2/thread. chunk i -> row i>>2, col (i&3)*8, LDS elems i*8.
        #pragma unroll
        for (int t = 0; t < 2; ++t) {
            int i = tid + t * TM * 2;
            dma16(A + (size_t)(m0 + (i >> 2)) * K + k0 + (i & 3) * 8,
                  As + t * TM * 16 + wave * 512);
        }
        // B: 512 16B chunks.
        #pragma unroll
        for (int t = 0; t < 512 / (TM * 2); ++t) {
            int i = tid + t * TM * 2;
            dma16(B + (size_t)(n0 + (i >> 2)) * K + k0 + (i & 3) * 8,
                  Bs + t * TM * 16 + wave * 512);
        }
        __syncthreads();   // drains vmcnt; tiles valid

        bf16x8 af[4], bff[4];
        #pragma unroll
        for (int mt = 0; mt < 4; ++mt)
            af[mt] = *(const bf16x8*)(As + (wm + mt * 16 + l15) * 32 + quad * 8);
        #pragma unroll
        for (int nt = 0; nt < 4; ++nt)
            bff[nt] = *(const bf16x8*)(Bs + (wn + nt * 16 + l15) * 32 + quad * 8);
        #pragma unroll
        for (int mt = 0; mt < 4; ++mt)
            #pragma unroll
            for (int nt = 0; nt < 4; ++nt)
                acc[mt][nt] = mfma32(af[mt], bff[nt], acc[mt][nt]);
        __syncthreads();
    }

    if constexpr (MODE == 0) {
        if (n0 < 384) {            // Q region: row-major, pre-scaled
            #pragma unroll
            for (int nt = 0; nt < 4; ++nt) {
                int n = n0 + wn + nt * 16 + l15;
                float bv = bias[n];
                #pragma unroll
                for (int mt = 0; mt < 4; ++mt) {
                    int mbase = m0 + wm + mt * 16 + quad * 4;
                    #pragma unroll
                    for (int r = 0; r < 4; ++r)
                        qg[(size_t)(mbase + r) * 384 + n] = f2bf((acc[mt][nt][r] + bv) * 0.125f);
                }
            }
        } else if (n0 < 768) {     // K region: operand-order slabs
            #pragma unroll
            for (int nt = 0; nt < 4; ++nt) {
                int n = n0 + wn + nt * 16 + l15;
                float bv = bias[n];
                int c2 = n - 384;
                int h = c2 >> 6, ck = c2 & 63;
                int half = ck >> 5, qd = (ck >> 3) & 3, j = ck & 7;
                #pragma unroll
                for (int mt = 0; mt < 4; ++mt) {
                    int mbase = m0 + wm + mt * 16 + quad * 4;
                    #pragma unroll
                    for (int r = 0; r < 4; ++r) {
                        int tok = mbase + r;
                        int b = tok >> 10, kv = tok & 1023;
                        int kt = kv >> 4, lk = kv & 15;
                        kg[(size_t)(b * 6 + h) * 65536 +
                           ((((size_t)kt * 2 + half) * 4 + qd) * 16 + lk) * 8 + j]
                            = f2bf(acc[mt][nt][r] + bv);
                    }
                }
            }
        } else {                   // V region: operand-order slabs, packed r-contiguous
            #pragma unroll
            for (int nt = 0; nt < 4; ++nt) {
                int n = n0 + wn + nt * 16 + l15;
                float bv = bias[n];
                int c2 = n - 768;
                int h = c2 >> 6, d = c2 & 63;
                int dt = d >> 4, lv = d & 15;
                #pragma unroll
                for (int mt = 0; mt < 4; ++mt) {
                    int mbase = m0 + wm + mt * 16 + quad * 4;   // multiple of 4
                    int b = mbase >> 10, kvb = mbase & 1023;
                    int cc = kvb >> 6, jt = (kvb >> 4) & 3, qd = (kvb >> 2) & 3;
                    ushort4v pk;
                    #pragma unroll
                    for (int r = 0; r < 4; ++r) pk[r] = f2bf(acc[mt][nt][r] + bv);
                    *(ushort4v*)(vg + (size_t)(b * 6 + h) * 65536 + (size_t)cc * 4096 +
                                 (((jt * 4 + dt) * 4 + qd) * 16 + lv) * 4) = pk;
                }
            }
        }
    } else {
        #pragma unroll
        for (int nt = 0; nt < 4; ++nt) {
            int n = n0 + wn + nt * 16 + l15;
            float bv = bias[n];
            #pragma unroll
            for (int mt = 0; mt < 4; ++mt) {
                int mbase = m0 + wm + mt * 16 + quad * 4;
                #pragma unroll
                for (int r = 0; r < 4; ++r)
                    out[(size_t)(mbase + r) * N + n] = acc[mt][nt][r] + bv;
            }
        }
    }
}

// Flash attention, LDS-staged (m97 pattern). Block = (qt 64 rows, h, b); 4 waves x 16 q.
// kv-chunk 64: K 8KB + V 8KB DMA'd per chunk; 4 inner steps of 16 kv.
// S^T trick + mfma16 PV; lane mappings identical to R5 (validated).
__global__ __launch_bounds__(256) void attn_fused(
    const unsigned short* __restrict__ qg,
    const unsigned short* __restrict__ kg,
    const unsigned short* __restrict__ vg,
    unsigned short* __restrict__ aout)   // [8192][384] bf16
{
    const int tid  = threadIdx.x;
    const int wave = tid >> 6;
    const int lane = tid & 63;
    const int l15  = lane & 15;
    const int quad = lane >> 4;
    const int qt = blockIdx.x;   // 0..15
    const int h  = blockIdx.y;   // 0..5
    const int b  = blockIdx.z;   // 0..7

    const size_t rowbase = (size_t)b * 1024;
    const unsigned short* Kslab = kg + (size_t)(b * 6 + h) * 65536;
    const unsigned short* Vslab = vg + (size_t)(b * 6 + h) * 65536;
    const int q0 = qt * 64 + wave * 16;

    __shared__ __align__(16) unsigned short Kb[4096];
    __shared__ __align__(16) unsigned short Vb[4096];

    bf16x8 aq0, aq1;
    {
        const unsigned short* qrow = qg + (rowbase + q0 + l15) * 384 + h * 64 + quad * 8;
        aq0 = *(const bf16x8*)qrow;
        aq1 = *(const bf16x8*)(qrow + 32);
    }

    f32x4 accO[4];
    #pragma unroll
    for (int dt = 0; dt < 4; ++dt) accO[dt] = (f32x4){0.f, 0.f, 0.f, 0.f};
    float lsum = 0.f;

    for (int c = 0; c < 16; ++c) {
        // Stage chunk c: contiguous 4096-elem copies (operand-order preserved by DMA).
        #pragma unroll
        for (int t = 0; t < 2; ++t) {
            int i = tid + t * 256;
            dma16(Kslab + (size_t)c * 4096 + i * 8, Kb + t * 2048 + wave * 512);
            dma16(Vslab + (size_t)c * 4096 + i * 8, Vb + t * 2048 + wave * 512);
        }
        __syncthreads();   // drains vmcnt; Kb/Vb valid

        #pragma unroll
        for (int kt = 0; kt < 4; ++kt) {
            bf16x8 ka = *(const bf16x8*)(Kb + (((kt * 2 + 0) * 4 + quad) * 16 + l15) * 8);
            bf16x8 kb = *(const bf16x8*)(Kb + (((kt * 2 + 1) * 4 + quad) * 16 + l15) * 8);
            f32x4 z = (f32x4){0.f, 0.f, 0.f, 0.f};
            z = mfma32(ka, aq0, z);
            z = mfma32(kb, aq1, z);    // S^T[kv=quad*4+r][q=l15]

            short4v p;
            #pragma unroll
            for (int r = 0; r < 4; ++r) {
                float s = z[r];
                s = (s < 0.f) ? 0.f : __expf(s);   // threshold mask -> exact 0 (matches ref)
                lsum += s;
                p[r] = (short)f2bf(s);
            }
            #pragma unroll
            for (int dt = 0; dt < 4; ++dt) {
                short4v vv = *(const short4v*)(Vb + (((kt * 4 + dt) * 4 + quad) * 16 + l15) * 4);
                accO[dt] = mfma16(vv, p, accO[dt]);
            }
        }
        __syncthreads();   // reads done before next chunk overwrites
    }

    lsum += __shfl_xor(lsum, 16, 64);
    lsum += __shfl_xor(lsum, 32, 64);
    float inv = 1.0f / lsum;

    unsigned short* orow = aout + (rowbase + q0 + l15) * 384 + h * 64 + quad * 4;
    #pragma unroll
    for (int dt = 0; dt < 4; ++dt) {
        ushort4v pk;
        #pragma unroll
        for (int r = 0; r < 4; ++r) pk[r] = f2bf(accO[dt][r] * inv);
        *(ushort4v*)(orow + dt * 16) = pk;
    }
}

extern "C" void kernel_launch(void* const* d_in, const int* in_sizes, int n_in,
                              void* d_out, int out_size, void* d_ws, size_t ws_size,
                              hipStream_t stream) {
    const float* x      = (const float*)d_in[0];  // [8,1024,384]
    const float* w_qkv  = (const float*)d_in[1];  // [1152,384]
    const float* b_qkv  = (const float*)d_in[2];  // [1152]
    const float* w_proj = (const float*)d_in[3];  // [384,384]
    const float* b_proj = (const float*)d_in[4];  // [384]
    float* out = (float*)d_out;                   // [8,1024,384]

    unsigned short* qg   = (unsigned short*)d_ws;            // 8192*384
    unsigned short* kgp  = qg   + (size_t)NX;                // 48*65536
    unsigned short* vgp  = kgp  + (size_t)NX;                // 48*65536
    unsigned short* aout = vgp  + (size_t)NX;                // 8192*384
    unsigned short* xb   = aout + (size_t)NX;                // 8192*384
    unsigned short* wqb  = xb   + (size_t)NX;                // 1152*384
    unsigned short* wpb  = wqb  + (size_t)NQ;                // 384*384

    cvt_bf16<<<3648, 256, 0, stream>>>(x, w_qkv, w_proj, xb, wqb, wpb);
    gemm_bt<0, 256><<<dim3(32, 9), 512, 0, stream>>>(
        xb, wqb, b_qkv, qg, kgp, vgp, nullptr, 8192, 1152, 384);
    attn_fused<<<dim3(16, 6, 8), 256, 0, stream>>>(qg, kgp, vgp, aout);
    gemm_bt<1, 128><<<dim3(64, 3), 256, 0, stream>>>(
        aout, wpb, b_proj, nullptr, nullptr, nullptr, out, 8192, 384, 384);
}

// Round 9
// 128.545 us; speedup vs baseline: 1.9206x; 1.0318x over previous
//
#include <hip/hip_runtime.h>
#include <hip/hip_bf16.h>

// R9 = R8 restructured for latency: single-barrier double-buffered LDS pipelines
// (prefetch chunk c+1's global_load_lds BEFORE computing chunk c; one __syncthreads
// per iteration — its vmcnt(0) drain overlaps the previous compute phase) in all
// three MFMA kernels, plus an XCD-locality swizzle in attn (all 16 q-tiles of one
// (b,h) slab land on the same XCD: slab = blockIdx.x % 48, 48 = 0 mod 8).
//   cvt(x,wq,wp -> bf16)
//   gemm<0,256>: qkv GEMM @512thr; epilogue: q row-major (pre-scaled 0.125),
//                K/V in MFMA-operand-order slabs per (b,h).
//   attn:        dbuf LDS staging, S^T trick + mfma16 PV (R5-validated mappings).
//   gemm<1,128>: proj -> fp32 out @256thr.
// ws (ushort elems): qg 3145728 | kg 3145728 | vg 3145728 | aout 3145728 | xb 3145728
//                    | wqb 442368 | wpb 147456  => 32.5 MB.

typedef __attribute__((__ext_vector_type__(8))) __bf16 bf16x8;
typedef __attribute__((__ext_vector_type__(8))) unsigned short ushort8;
typedef __attribute__((__ext_vector_type__(4))) unsigned short ushort4v;
typedef __attribute__((__ext_vector_type__(4))) short short4v;
typedef __attribute__((__ext_vector_type__(4))) float f32x4;

#define NX 3145728   // 8192*384
#define NQ 442368    // 1152*384
#define NP 147456    // 384*384

__device__ __forceinline__ f32x4 mfma32(bf16x8 a, bf16x8 b, f32x4 c) {
    return __builtin_amdgcn_mfma_f32_16x16x32_bf16(a, b, c, 0, 0, 0);
}
__device__ __forceinline__ f32x4 mfma16(short4v a, short4v b, f32x4 c) {
    return __builtin_amdgcn_mfma_f32_16x16x16bf16_1k(a, b, c, 0, 0, 0);
}

__device__ __forceinline__ unsigned short f2bf(float f) {
    union { float f; unsigned int i; } x; x.f = f;
    unsigned int u = x.i;
    return (unsigned short)((u + 0x7fffu + ((u >> 16) & 1u)) >> 16);
}

__device__ __forceinline__ void dma16(const unsigned short* g, unsigned short* l) {
    __builtin_amdgcn_global_load_lds(
        (const __attribute__((address_space(1))) unsigned int*)g,
        (__attribute__((address_space(3))) unsigned int*)l, 16, 0, 0);
}

// fp32 -> bf16 for x, w_qkv, w_proj. 4 elems/thread.
__global__ __launch_bounds__(256) void cvt_bf16(
    const float* __restrict__ x, const float* __restrict__ wq, const float* __restrict__ wp,
    unsigned short* __restrict__ xb, unsigned short* __restrict__ wqb, unsigned short* __restrict__ wpb)
{
    int i = blockIdx.x * 256 + threadIdx.x;
    const float* src; unsigned short* dst; int off;
    if (i < NX / 4)              { src = x;  dst = xb;  off = i * 4; }
    else if (i < (NX + NQ) / 4)  { src = wq; dst = wqb; off = i * 4 - NX; }
    else                         { src = wp; dst = wpb; off = i * 4 - NX - NQ; }
    float4 v = *(const float4*)(src + off);
    ushort4v r;
    r[0] = f2bf(v.x); r[1] = f2bf(v.y); r[2] = f2bf(v.z); r[3] = f2bf(v.w);
    *(ushort4v*)(dst + off) = r;
}

// C = A[M,K] @ B[N,K]^T + bias. bf16 in, fp32 acc, TMx128 tile, BK=32.
// Single-barrier double-buffered DMA pipeline. THREADS = 2*TM.
// MODE 0 (QKV): n<384 -> qg row-major *0.125 ; 384..768 -> kg operand-order ; >=768 -> vg.
//   kg slab (b,h) [64 kt][2 half][4 quad][16 l15][8 j]: K[kv=kt*16+l15][c=half*32+quad*8+j]
//   vg slab (b,h) [16 c][4 jt][4 dt][4 quad][16 l15][4 j]: V^T[d=dt*16+l15][kv=c*64+jt*16+quad*4+j]
// MODE 1 (proj): fp32 out + bias.
template <int MODE, int TM>
__global__ __launch_bounds__(TM * 2) void gemm_bt(
    const unsigned short* __restrict__ A,
    const unsigned short* __restrict__ B,
    const float* __restrict__ bias,
    unsigned short* __restrict__ qg,
    unsigned short* __restrict__ kg,
    unsigned short* __restrict__ vg,
    float* __restrict__ out,
    int M, int N, int K)
{
    const int tid  = threadIdx.x;
    const int lane = tid & 63;
    const int wave = tid >> 6;
    const int l15  = lane & 15;
    const int quad = lane >> 4;
    const int m0 = blockIdx.x * TM;
    const int n0 = blockIdx.y * 128;
    const int wm = (wave >> 1) * 64;
    const int wn = (wave & 1) * 64;

    __shared__ __align__(16) unsigned short As[2 * TM * 32];
    __shared__ __align__(16) unsigned short Bs[2 * 128 * 32];

    f32x4 acc[4][4];
    #pragma unroll
    for (int i = 0; i < 4; ++i)
        #pragma unroll
        for (int j = 0; j < 4; ++j)
            acc[i][j] = (f32x4){0.f, 0.f, 0.f, 0.f};

    // stage K-slice k0 into buffer buf
    auto stage = [&](int k0, int buf) {
        #pragma unroll
        for (int t = 0; t < 2; ++t) {
            int i = tid + t * TM * 2;
            dma16(A + (size_t)(m0 + (i >> 2)) * K + k0 + (i & 3) * 8,
                  As + buf * TM * 32 + t * TM * 16 + wave * 512);
        }
        #pragma unroll
        for (int t = 0; t < 512 / (TM * 2); ++t) {
            int i = tid + t * TM * 2;
            dma16(B + (size_t)(n0 + (i >> 2)) * K + k0 + (i & 3) * 8,
                  Bs + buf * 4096 + t * TM * 16 + wave * 512);
        }
    };

    const int nk = K >> 5;   // 12
    stage(0, 0);
    for (int ki = 0; ki < nk; ++ki) {
        __syncthreads();                       // drains DMA for buf ki&1; syncs compute ki-1
        if (ki + 1 < nk) stage((ki + 1) << 5, (ki + 1) & 1);   // in flight during compute
        const unsigned short* as = As + (ki & 1) * TM * 32;
        const unsigned short* bs = Bs + (ki & 1) * 4096;

        bf16x8 af[4], bff[4];
        #pragma unroll
        for (int mt = 0; mt < 4; ++mt)
            af[mt] = *(const bf16x8*)(as + (wm + mt * 16 + l15) * 32 + quad * 8);
        #pragma unroll
        for (int nt = 0; nt < 4; ++nt)
            bff[nt] = *(const bf16x8*)(bs + (wn + nt * 16 + l15) * 32 + quad * 8);
        #pragma unroll
        for (int mt = 0; mt < 4; ++mt)
            #pragma unroll
            for (int nt = 0; nt < 4; ++nt)
                acc[mt][nt] = mfma32(af[mt], bff[nt], acc[mt][nt]);
    }

    if constexpr (MODE == 0) {
        if (n0 < 384) {            // Q region: row-major, pre-scaled
            #pragma unroll
            for (int nt = 0; nt < 4; ++nt) {
                int n = n0 + wn + nt * 16 + l15;
                float bv = bias[n];
                #pragma unroll
                for (int mt = 0; mt < 4; ++mt) {
                    int mbase = m0 + wm + mt * 16 + quad * 4;
                    #pragma unroll
                    for (int r = 0; r < 4; ++r)
                        qg[(size_t)(mbase + r) * 384 + n] = f2bf((acc[mt][nt][r] + bv) * 0.125f);
                }
            }
        } else if (n0 < 768) {     // K region: operand-order slabs
            #pragma unroll
            for (int nt = 0; nt < 4; ++nt) {
                int n = n0 + wn + nt * 16 + l15;
                float bv = bias[n];
                int c2 = n - 384;
                int h = c2 >> 6, ck = c2 & 63;
                int half = ck >> 5, qd = (ck >> 3) & 3, j = ck & 7;
                #pragma unroll
                for (int mt = 0; mt < 4; ++mt) {
                    int mbase = m0 + wm + mt * 16 + quad * 4;
                    #pragma unroll
                    for (int r = 0; r < 4; ++r) {
                        int tok = mbase + r;
                        int b = tok >> 10, kv = tok & 1023;
                        int kt = kv >> 4, lk = kv & 15;
                        kg[(size_t)(b * 6 + h) * 65536 +
                           ((((size_t)kt * 2 + half) * 4 + qd) * 16 + lk) * 8 + j]
                            = f2bf(acc[mt][nt][r] + bv);
                    }
                }
            }
        } else {                   // V region: operand-order slabs, packed r-contiguous
            #pragma unroll
            for (int nt = 0; nt < 4; ++nt) {
                int n = n0 + wn + nt * 16 + l15;
                float bv = bias[n];
                int c2 = n - 768;
                int h = c2 >> 6, d = c2 & 63;
                int dt = d >> 4, lv = d & 15;
                #pragma unroll
                for (int mt = 0; mt < 4; ++mt) {
                    int mbase = m0 + wm + mt * 16 + quad * 4;   // multiple of 4
                    int b = mbase >> 10, kvb = mbase & 1023;
                    int cc = kvb >> 6, jt = (kvb >> 4) & 3, qd = (kvb >> 2) & 3;
                    ushort4v pk;
                    #pragma unroll
                    for (int r = 0; r < 4; ++r) pk[r] = f2bf(acc[mt][nt][r] + bv);
                    *(ushort4v*)(vg + (size_t)(b * 6 + h) * 65536 + (size_t)cc * 4096 +
                                 (((jt * 4 + dt) * 4 + qd) * 16 + lv) * 4) = pk;
                }
            }
        }
    } else {
        #pragma unroll
        for (int nt = 0; nt < 4; ++nt) {
            int n = n0 + wn + nt * 16 + l15;
            float bv = bias[n];
            #pragma unroll
            for (int mt = 0; mt < 4; ++mt) {
                int mbase = m0 + wm + mt * 16 + quad * 4;
                #pragma unroll
                for (int r = 0; r < 4; ++r)
                    out[(size_t)(mbase + r) * N + n] = acc[mt][nt][r] + bv;
            }
        }
    }
}

// Flash attention, dbuf LDS pipeline + XCD-locality swizzle.
// Linear grid 768: slab s = id % 48 (= b*6+h, pins all 16 q-tiles of a slab to XCD s%8),
// qt = id / 48. 4 waves x 16 q-rows. kv-chunk 64 (K 8KB + V 8KB per buffer).
// S^T trick + mfma16 PV; lane mappings identical to R5 (validated).
__global__ __launch_bounds__(256) void attn_fused(
    const unsigned short* __restrict__ qg,
    const unsigned short* __restrict__ kg,
    const unsigned short* __restrict__ vg,
    unsigned short* __restrict__ aout)   // [8192][384] bf16
{
    const int tid  = threadIdx.x;
    const int wave = tid >> 6;
    const int lane = tid & 63;
    const int l15  = lane & 15;
    const int quad = lane >> 4;
    const int id = blockIdx.x;
    const int s  = id % 48;      // slab = b*6+h  (id%8 == s%8 -> same XCD per slab)
    const int qt = id / 48;      // 0..15
    const int b  = s / 6;
    const int h  = s % 6;

    const size_t rowbase = (size_t)b * 1024;
    const unsigned short* Kslab = kg + (size_t)s * 65536;
    const unsigned short* Vslab = vg + (size_t)s * 65536;
    const int q0 = qt * 64 + wave * 16;

    __shared__ __align__(16) unsigned short Kb[2 * 4096];
    __shared__ __align__(16) unsigned short Vb[2 * 4096];

    bf16x8 aq0, aq1;
    {
        const unsigned short* qrow = qg + (rowbase + q0 + l15) * 384 + h * 64 + quad * 8;
        aq0 = *(const bf16x8*)qrow;
        aq1 = *(const bf16x8*)(qrow + 32);
    }

    f32x4 accO[4];
    #pragma unroll
    for (int dt = 0; dt < 4; ++dt) accO[dt] = (f32x4){0.f, 0.f, 0.f, 0.f};
    float lsum = 0.f;

    auto stage = [&](int c, int buf) {
        #pragma unroll
        for (int t = 0; t < 2; ++t) {
            int i = tid + t * 256;
            dma16(Kslab + (size_t)c * 4096 + i * 8, Kb + buf * 4096 + t * 2048 + wave * 512);
            dma16(Vslab + (size_t)c * 4096 + i * 8, Vb + buf * 4096 + t * 2048 + wave * 512);
        }
    };

    stage(0, 0);
    for (int c = 0; c < 16; ++c) {
        __syncthreads();                          // drains chunk c's DMA; syncs compute c-1
        if (c + 1 < 16) stage(c + 1, (c + 1) & 1);   // in flight during compute of c
        const unsigned short* kb = Kb + (c & 1) * 4096;
        const unsigned short* vb = Vb + (c & 1) * 4096;

        #pragma unroll
        for (int kt = 0; kt < 4; ++kt) {
            bf16x8 ka = *(const bf16x8*)(kb + (((kt * 2 + 0) * 4 + quad) * 16 + l15) * 8);
            bf16x8 kbf = *(const bf16x8*)(kb + (((kt * 2 + 1) * 4 + quad) * 16 + l15) * 8);
            f32x4 z = (f32x4){0.f, 0.f, 0.f, 0.f};
            z = mfma32(ka, aq0, z);
            z = mfma32(kbf, aq1, z);   // S^T[kv=quad*4+r][q=l15]

            short4v p;
            #pragma unroll
            for (int r = 0; r < 4; ++r) {
                float sc = z[r];
                sc = (sc < 0.f) ? 0.f : __expf(sc);   // threshold mask -> exact 0 (matches ref)
                lsum += sc;
                p[r] = (short)f2bf(sc);
            }
            #pragma unroll
            for (int dt = 0; dt < 4; ++dt) {
                short4v vv = *(const short4v*)(vb + (((kt * 4 + dt) * 4 + quad) * 16 + l15) * 4);
                accO[dt] = mfma16(vv, p, accO[dt]);
            }
        }
    }

    lsum += __shfl_xor(lsum, 16, 64);
    lsum += __shfl_xor(lsum, 32, 64);
    float inv = 1.0f / lsum;

    unsigned short* orow = aout + (rowbase + q0 + l15) * 384 + h * 64 + quad * 4;
    #pragma unroll
    for (int dt = 0; dt < 4; ++dt) {
        ushort4v pk;
        #pragma unroll
        for (int r = 0; r < 4; ++r) pk[r] = f2bf(accO[dt][r] * inv);
        *(ushort4v*)(orow + dt * 16) = pk;
    }
}

extern "C" void kernel_launch(void* const* d_in, const int* in_sizes, int n_in,
                              void* d_out, int out_size, void* d_ws, size_t ws_size,
                              hipStream_t stream) {
    const float* x      = (const float*)d_in[0];  // [8,1024,384]
    const float* w_qkv  = (const float*)d_in[1];  // [1152,384]
    const float* b_qkv  = (const float*)d_in[2];  // [1152]
    const float* w_proj = (const float*)d_in[3];  // [384,384]
    const float* b_proj = (const float*)d_in[4];  // [384]
    float* out = (float*)d_out;                   // [8,1024,384]

    unsigned short* qg   = (unsigned short*)d_ws;            // 8192*384
    unsigned short* kgp  = qg   + (size_t)NX;                // 48*65536
    unsigned short* vgp  = kgp  + (size_t)NX;                // 48*65536
    unsigned short* aout = vgp  + (size_t)NX;                // 8192*384
    unsigned short* xb   = aout + (size_t)NX;                // 8192*384
    unsigned short* wqb  = xb   + (size_t)NX;                // 1152*384
    unsigned short* wpb  = wqb  + (size_t)NQ;                // 384*384

    cvt_bf16<<<3648, 256, 0, stream>>>(x, w_qkv, w_proj, xb, wqb, wpb);
    gemm_bt<0, 256><<<dim3(32, 9), 512, 0, stream>>>(
        xb, wqb, b_qkv, qg, kgp, vgp, nullptr, 8192, 1152, 384);
    attn_fused<<<768, 256, 0, stream>>>(qg, kgp, vgp, aout);
    gemm_bt<1, 128><<<dim3(64, 3), 256, 0, stream>>>(
        aout, wpb, b_proj, nullptr, nullptr, nullptr, out, 8192, 384, 384);
}